// Round 7
// baseline (79.939 us; speedup 1.0000x reference)
//
#include <hip/hip_runtime.h>
#include <math.h>

// (B, N, D) = (32, 128, 128)
#define BATCH 32
#define NN    128
#define AP    132     // full-path adjf fp32 pitch
#define BP    136     // bf16 pitch (shorts); rows 272B -> 16B aligned
#define NT    512     // 8 waves
#define EPS   6e-3f
#define MROW  32      // fast path: maintained rows (block-diagonal structure)

typedef short frag8 __attribute__((ext_vector_type(8)));
typedef float f32x4 __attribute__((ext_vector_type(4)));

__device__ __forceinline__ short bf16c(float f) {
    unsigned u = __float_as_uint(f);
    unsigned r = (u + 0x7fffu + ((u >> 16) & 1u)) >> 16;
    return (short)r;
}
__device__ __forceinline__ float bf2f(short s) {
    return __uint_as_float(((unsigned)(unsigned short)s) << 16);
}

// ---------- full-path helper (round-6, validated) ----------
__device__ void mm_xw2(short* __restrict__ abuf, short* __restrict__ xT,
                       const frag8 wf[4][2], int wr, int wc, int l15, int quad,
                       int lane, float* ssp) {
    const f32x4 z = {0.f, 0.f, 0.f, 0.f};
    f32x4 acc[4][2];
    #pragma unroll
    for (int tr = 0; tr < 4; ++tr) { acc[tr][0] = z; acc[tr][1] = z; }
    #pragma unroll
    for (int ks = 0; ks < 4; ++ks) {
        const int kb = ks * 32 + quad * 8;
        #pragma unroll
        for (int tr = 0; tr < 4; ++tr) {
            frag8 a = *(const frag8*)&abuf[(wr * 64 + tr * 16 + l15) * BP + kb];
            acc[tr][0] = __builtin_amdgcn_mfma_f32_16x16x32_bf16(a, wf[ks][0], acc[tr][0], 0, 0, 0);
            acc[tr][1] = __builtin_amdgcn_mfma_f32_16x16x32_bf16(a, wf[ks][1], acc[tr][1], 0, 0, 0);
        }
    }
    __syncthreads();
    float lss = 0.f;
    #pragma unroll
    for (int tr = 0; tr < 4; ++tr)
        #pragma unroll
        for (int c2 = 0; c2 < 2; ++c2) {
            const int n  = wc * 32 + c2 * 16 + l15;
            const int m0 = wr * 64 + tr * 16 + quad * 4;
            f32x4 v = acc[tr][c2];
            float r0 = v[0] > 0.f ? v[0] : 0.f;
            float r1 = v[1] > 0.f ? v[1] : 0.f;
            float r2 = v[2] > 0.f ? v[2] : 0.f;
            float r3 = v[3] > 0.f ? v[3] : 0.f;
            lss = fmaf(r0, r0, lss); lss = fmaf(r1, r1, lss);
            lss = fmaf(r2, r2, lss); lss = fmaf(r3, r3, lss);
            short4 p; p.x = bf16c(r0); p.y = bf16c(r1);
            p.z = bf16c(r2); p.w = bf16c(r3);
            *(short4*)&xT[n * BP + m0] = p;
            abuf[(m0 + 0) * BP + n] = p.x;
            abuf[(m0 + 1) * BP + n] = p.y;
            abuf[(m0 + 2) * BP + n] = p.z;
            abuf[(m0 + 3) * BP + n] = p.w;
        }
    #pragma unroll
    for (int off = 32; off >= 1; off >>= 1) lss += __shfl_down(lss, off);
    if (lane == 0) atomicAdd(ssp, lss);
    __syncthreads();
}

// ---------- fast-path F: x_new(32x128) = relu(ysel @ W), bf16 MFMA ----------
// ysel row r = (r <= isel) ? ya : xa. Writes xa row-major + ||x||_F^2.
__device__ __forceinline__ void fsmall(short* __restrict__ xa,
                                       const short* __restrict__ ya, int isel,
                                       const frag8 wf[4][2],
                                       int w, int lane, float* Sp) {
    const int l15 = lane & 15, quad = lane >> 4;
    const int rt = w & 1, ct = w >> 1;          // 2 row-tiles x 4 col-tiles
    const int r = rt * 16 + l15;
    const short* src = (r <= isel) ? ya : xa;
    const f32x4 z = {0.f, 0.f, 0.f, 0.f};
    f32x4 a0 = z, a1 = z;
    #pragma unroll
    for (int ks = 0; ks < 4; ++ks) {
        const int kb = ks * 32 + quad * 8;
        frag8 a = *(const frag8*)&src[r * BP + kb];
        a0 = __builtin_amdgcn_mfma_f32_16x16x32_bf16(a, wf[ks][0], a0, 0, 0, 0);
        a1 = __builtin_amdgcn_mfma_f32_16x16x32_bf16(a, wf[ks][1], a1, 0, 0, 0);
    }
    __syncthreads();     // all reads of xa/ya done before overwriting xa
    float lss = 0.f;
    #pragma unroll
    for (int c2 = 0; c2 < 2; ++c2) {
        const int e  = ct * 32 + c2 * 16 + l15;
        const int m0 = rt * 16 + quad * 4;
        f32x4 v = (c2 == 0) ? a0 : a1;
        #pragma unroll
        for (int jj = 0; jj < 4; ++jj) {
            float rr = v[jj] > 0.f ? v[jj] : 0.f;
            lss = fmaf(rr, rr, lss);
            xa[(m0 + jj) * BP + e] = bf16c(rr);
        }
    }
    #pragma unroll
    for (int off = 32; off >= 1; off >>= 1) lss += __shfl_down(lss, off);
    if (lane == 0) atomicAdd(Sp, lss);
    __syncthreads();
}

__global__ __launch_bounds__(NT, 1)
void gcn_kernel(const float* __restrict__ xin,
                const float* __restrict__ W,
                float* __restrict__ out) {
    extern __shared__ char smem_raw[];
    __shared__ float s_wn, s_x0max, s_S, s_sprob, s_aii;

    const int t = threadIdx.x;
    const int b = blockIdx.x;
    const int lane = t & 63, w = t >> 6;
    const int l15 = lane & 15, quad = lane >> 4;

    const float* xin_b = xin + (size_t)b * NN * NN;
    float*       out_b = out + (size_t)b * NN * NN;

    // =============== prelude: wnorm, per-row ||xin_r||^2, zero out ===========
    float* rowsq = (float*)smem_raw;                 // [128], consumed before paths
    if (t < NN) rowsq[t] = 0.f;
    if (t == 0) { s_wn = 0.f; s_x0max = 0.f; s_S = 0.f; s_sprob = 0.f; }
    __syncthreads();
    {
        float lw = 0.f;
        #pragma unroll
        for (int k = 0; k < 8; ++k) {
            float4 f = ((const float4*)W)[k * NT + t];
            lw = fmaf(f.x, f.x, lw); lw = fmaf(f.y, f.y, lw);
            lw = fmaf(f.z, f.z, lw); lw = fmaf(f.w, f.w, lw);
        }
        #pragma unroll
        for (int off = 32; off >= 1; off >>= 1) lw += __shfl_down(lw, off);
        if (lane == 0) atomicAdd(&s_wn, lw);
    }
    #pragma unroll
    for (int k = 0; k < 8; ++k) {
        const int v = k * NT + t;                    // f4 idx; row = v>>5
        float4 f = ((const float4*)xin_b)[v];
        float s = fmaf(f.x, f.x, fmaf(f.y, f.y, fmaf(f.z, f.z, f.w * f.w)));
        atomicAdd(&rowsq[v >> 5], s);
    }
    {
        float4 zz = {0.f, 0.f, 0.f, 0.f};
        #pragma unroll
        for (int k = 0; k < 8; ++k) ((float4*)out_b)[k * NT + t] = zz;
    }
    __syncthreads();
    if (t < NN) atomicMax((int*)&s_x0max, __float_as_int(rowsq[t]));
    __syncthreads();
    const float wn = s_wn;
    bool fast;
    {
        float u = s_x0max;
        #pragma unroll
        for (int k = 0; k < 32; ++k) u *= wn;        // X0max * wn^32
        fast = (wn <= 1.0f) && (u < EPS);
    }

    // =============== FAST PATH: 32-row lazy window ===========================
    // LDS: adjb[32][33] f32 | rsA[32] rsB[32] probf[32] | xa[32][BP] ya[32][BP] | wt[128][BP]
    float* adjb = (float*)(smem_raw + 512);
    float* rsA  = adjb + 32 * 33;
    float* rsB  = rsA + 32;
    float* probf = rsB + 32;
    short* xa = (short*)(probf + 32);
    short* ya = xa + 32 * BP;
    short* wt = ya + 32 * BP;

    frag8 wfrag[4][2];

    if (fast) {
        if (t < NN) out_b[t * NN + t] = 1.0f;        // diag (ordered after zero: barrier above)
        // stage xin rows 0..31 -> ya bf16
        #pragma unroll
        for (int k = 0; k < 2; ++k) {
            const int v = k * NT + t;                // f4 idx < 1024
            float4 f = ((const float4*)xin_b)[v];
            const int r = v >> 5, c = (v & 31) * 4;
            short4 p; p.x = bf16c(f.x); p.y = bf16c(f.y); p.z = bf16c(f.z); p.w = bf16c(f.w);
            *(short4*)&ya[r * BP + c] = p;
        }
        // stage WT bf16
        #pragma unroll
        for (int k = 0; k < 8; ++k) {
            const int idx = k * NT + t;
            float4 f = ((const float4*)W)[idx];
            const int e0 = idx * 4, d = e0 >> 7, e = e0 & 127;
            wt[(e + 0) * BP + d] = bf16c(f.x);
            wt[(e + 1) * BP + d] = bf16c(f.y);
            wt[(e + 2) * BP + d] = bf16c(f.z);
            wt[(e + 3) * BP + d] = bf16c(f.w);
        }
        if (t < MROW) rsA[t] = 1.0f;
        __syncthreads();
        // wfrag preload: B[k=d][n=e] = W[d][e]; col mapping matches fsmall (ct = w>>1)
        #pragma unroll
        for (int ks = 0; ks < 4; ++ks)
            #pragma unroll
            for (int c2 = 0; c2 < 2; ++c2) {
                const int e  = (w >> 1) * 32 + c2 * 16 + l15;
                const int kb = ks * 32 + quad * 8;
                wfrag[ks][c2] = *(const frag8*)&wt[e * BP + kb];
            }
        // x0 = relu(xin[0..31] @ W) -> xa, S1
        fsmall(xa, ya, 31, wfrag, w, lane, &s_S);
        // certificate (c): S1 * wn^31 < EPS ensures S<EPS strictly before i=32
        {
            float u = s_S;
            #pragma unroll
            for (int k = 0; k < 31; ++k) u *= wn;
            if (u >= EPS) fast = false;              // uniform; fall back to full path
        }
    }

    if (fast) {
        bool skip = (s_S < EPS);
        int par = 0;
        for (int i = 1; i < NN; ++i) {
            if (skip || i >= MROW) break;            // out already complete
            float* rs_rd = (par == 0) ? rsA : rsB;
            float* rs_wr = (par == 0) ? rsB : rsA;

            // --- P: prob[j<i] = dot(x_j, x_i) fp32; write out row/col i; sprob
            {
                const int j = t >> 2, q = t & 3;
                float sp = 0.f;
                if (j < i) {
                    const short* xj = &xa[j * BP + q * 32];
                    const short* xi = &xa[i * BP + q * 32];
                    float s = 0.f;
                    #pragma unroll
                    for (int dd = 0; dd < 4; ++dd) {
                        frag8 aj = *(const frag8*)&xj[dd * 8];
                        frag8 ai = *(const frag8*)&xi[dd * 8];
                        #pragma unroll
                        for (int u = 0; u < 8; ++u)
                            s = fmaf(bf2f(aj[u]), bf2f(ai[u]), s);
                    }
                    s += __shfl_down(s, 2, 4);
                    s += __shfl_down(s, 1, 4);
                    if (q == 0) {
                        probf[j] = s;
                        out_b[i * NN + j] = s;
                        out_b[j * NN + i] = s;
                        sp = s;
                    }
                }
                #pragma unroll
                for (int off = 32; off >= 1; off >>= 1) sp += __shfl_down(sp, off);
                if (lane == 0) atomicAdd(&s_sprob, sp);
            }
            __syncthreads();

            // --- QD: extend + normalize (i+1)^2 block; new rowsums (dbuf); reset S
            {
                const float spr = s_sprob;
                const int c = t & 31, r0 = t >> 5;   // r0 in 0..15; rows r0, r0+16
                const float dc = (c <= i)
                    ? (1.0f / sqrtf((c == i) ? (1.f + spr) : (rs_rd[c] + probf[c]))) : 0.f;
                float nv[2];
                #pragma unroll
                for (int p = 0; p < 2; ++p) {
                    const int r = r0 + 16 * p;
                    float v = 0.f;
                    if (r <= i && c <= i) {
                        float dr = 1.0f / sqrtf((r == i) ? (1.f + spr)
                                                         : (rs_rd[r] + probf[r]));
                        float val = (r == i) ? ((c == i) ? 1.f : probf[c])
                                             : ((c == i) ? probf[r] : adjb[r * 33 + c]);
                        v = dr * val * dc;
                    }
                    nv[p] = v;
                }
                #pragma unroll
                for (int p = 0; p < 2; ++p) {
                    const int r = r0 + 16 * p;
                    if (r <= i && c <= i) adjb[r * 33 + c] = nv[p];
                    float srs = nv[p];
                    srs += __shfl_down(srs, 16, 32);
                    srs += __shfl_down(srs, 8, 32);
                    srs += __shfl_down(srs, 4, 32);
                    srs += __shfl_down(srs, 2, 32);
                    srs += __shfl_down(srs, 1, 32);
                    if (c == 0 && r <= i) rs_wr[r] = srs;
                }
                if (t == NT - 1) s_S = 0.f;
            }
            __syncthreads();

            // --- E: y[r<=i] = sum_{c<=i} adjb[r][c] * x[c]  (rows > i: y = x, no copy)
            {
                const int e = t & 127, rg = t >> 7;
                float acc[8] = {0.f,0.f,0.f,0.f,0.f,0.f,0.f,0.f};
                for (int c = 0; c <= i; ++c) {
                    const float xv = bf2f(xa[c * BP + e]);
                    #pragma unroll
                    for (int p = 0; p < 8; ++p)
                        acc[p] = fmaf(adjb[(rg + 4 * p) * 33 + c], xv, acc[p]);
                }
                #pragma unroll
                for (int p = 0; p < 8; ++p) {
                    const int r = rg + 4 * p;
                    if (r <= i) ya[r * BP + e] = bf16c(acc[p]);
                }
                if (t == NT - 1) s_sprob = 0.f;
            }
            __syncthreads();

            // --- F: x = relu(ysel @ W) -> xa + S
            fsmall(xa, ya, i, wfrag, w, lane, &s_S);
            skip = (s_S < EPS);
            par ^= 1;
        }
        return;
    }

    // =============== FULL PATH (round-6, validated fallback) =================
    {
        float* adjf = (float*)smem_raw;              // [128][132]
        short* ybuf = (short*)(adjf + NN * AP);      // [128][136]
        short* xT   = ybuf + NN * BP;                // [128][136]
        float* prob = (float*)(xT + NN * BP);        // [128]
        float* dinv = prob + NN;                     // [128]
        float* rs   = dinv + NN;                     // [128]

        const int wr = w >> 2, wc = w & 3;

        if (t == 0) { s_S = 0.0f; s_sprob = 0.0f; }
        __syncthreads();

        for (int e = t; e < NN * AP; e += NT) adjf[e] = 0.0f;
        for (int v = t; v < NN * NN / 4; v += NT) {
            float4 f = ((const float4*)xin_b)[v];
            const int node = v >> 5, c = (v & 31) * 4;
            short4 p; p.x = bf16c(f.x); p.y = bf16c(f.y); p.z = bf16c(f.z); p.w = bf16c(f.w);
            *(short4*)&ybuf[node * BP + c] = p;
        }
        #pragma unroll
        for (int k = 0; k < 8; ++k) {
            const int idx = k * NT + t;
            float4 f = ((const float4*)W)[idx];
            const int e0 = idx * 4, d = e0 >> 7, e = e0 & 127;
            xT[(e + 0) * BP + d] = bf16c(f.x);
            xT[(e + 1) * BP + d] = bf16c(f.y);
            xT[(e + 2) * BP + d] = bf16c(f.z);
            xT[(e + 3) * BP + d] = bf16c(f.w);
        }
        __syncthreads();

        frag8 wf2[4][2];
        #pragma unroll
        for (int ks = 0; ks < 4; ++ks)
            #pragma unroll
            for (int c2 = 0; c2 < 2; ++c2) {
                const int e  = wc * 32 + c2 * 16 + l15;
                const int kb = ks * 32 + quad * 8;
                wf2[ks][c2] = *(const frag8*)&xT[e * BP + kb];
            }
        if (t < NN) {
            adjf[t * AP + t] = 1.0f;
            out_b[t * NN + t] = 1.0f;
            rs[t] = 1.0f;
        }
        const bool wok = (wn <= 1.0f);
        __syncthreads();

        mm_xw2(ybuf, xT, wf2, wr, wc, l15, quad, lane, &s_S);
        float ss = s_S;
        bool skip = (ss == 0.0f) || (wok && ss < EPS);

        for (int i = 1; i < NN; ++i) {
            if (skip) {
                const int i0 = i;
                const int nrow = NN - i0;
                for (int v = t; v < nrow * (NN / 4); v += NT) {
                    const int r = i0 + (v >> 5), c = (v & 31) * 4;
                    float4 zz = {0.f, 0.f, 0.f, 0.f};
                    *(float4*)&out_b[r * NN + c] = zz;
                }
                for (int v = t; v < i0 * nrow; v += NT) {
                    const int r = v / nrow, c = i0 + v % nrow;
                    out_b[r * NN + c] = 0.f;
                }
                __syncthreads();
                if (t >= i0 && t < NN) out_b[t * NN + t] = 1.0f;
                break;
            }

            {
                if (t == 0) s_aii = adjf[i * AP + i];
                const f32x4 z = {0.f, 0.f, 0.f, 0.f};
                f32x4 pa = z, pb = z;
                #pragma unroll
                for (int ks = 0; ks < 4; ++ks) {
                    const int kb = ks * 32 + quad * 8;
                    frag8 a  = *(const frag8*)&ybuf[(w * 16 + l15) * BP + kb];
                    frag8 bb = *(const frag8*)&ybuf[i * BP + kb];
                    if (ks & 1) pb = __builtin_amdgcn_mfma_f32_16x16x32_bf16(a, bb, pb, 0, 0, 0);
                    else        pa = __builtin_amdgcn_mfma_f32_16x16x32_bf16(a, bb, pa, 0, 0, 0);
                }
                f32x4 pc = pa + pb;
                float sp = 0.f;
                if (l15 == 0) {
                    #pragma unroll
                    for (int r = 0; r < 4; ++r) {
                        const int j = w * 16 + quad * 4 + r;
                        const float p = pc[r];
                        const bool m = (j < i);
                        prob[j] = m ? p : 0.f;
                        if (m) {
                            adjf[i * AP + j] = p;  adjf[j * AP + i] = p;
                            out_b[i * NN + j] = p; out_b[j * NN + i] = p;
                            sp += p;
                        }
                    }
                }
                sp += __shfl_down(sp, 32);
                sp += __shfl_down(sp, 16);
                if (lane == 0) atomicAdd(&s_sprob, sp);
            }
            __syncthreads();

            if (t < NN) {
                const float d = (t == i) ? (s_aii + s_sprob) : (rs[t] + prob[t]);
                dinv[t] = 1.0f / sqrtf(d);
            }
            if (t == NN) s_S = 0.f;
            __syncthreads();

            {
                const int r = t >> 2, q = t & 3;
                const float dr = dinv[r];
                float lrs = 0.f;
                #pragma unroll
                for (int g = 0; g < 8; ++g) {
                    const int c = q * 32 + g * 4;
                    float4 v4 = *(const float4*)&adjf[r * AP + c];
                    float4 d4 = *(const float4*)&dinv[c];
                    v4.x *= dr * d4.x; v4.y *= dr * d4.y;
                    v4.z *= dr * d4.z; v4.w *= dr * d4.w;
                    *(float4*)&adjf[r * AP + c] = v4;
                    lrs += (v4.x + v4.y) + (v4.z + v4.w);
                    short4 p; p.x = bf16c(v4.x); p.y = bf16c(v4.y);
                    p.z = bf16c(v4.z); p.w = bf16c(v4.w);
                    *(short4*)&ybuf[r * BP + c] = p;
                }
                lrs += __shfl_down(lrs, 2, 4);
                lrs += __shfl_down(lrs, 1, 4);
                if (q == 0) rs[r] = lrs;
                if (t == NT - 1) s_sprob = 0.f;
            }
            __syncthreads();

            {
                const f32x4 z = {0.f, 0.f, 0.f, 0.f};
                f32x4 acc[4][2];
                #pragma unroll
                for (int tr = 0; tr < 4; ++tr) { acc[tr][0] = z; acc[tr][1] = z; }
                #pragma unroll
                for (int ks = 0; ks < 4; ++ks) {
                    const int kb = ks * 32 + quad * 8;
                    frag8 b0 = *(const frag8*)&xT[(wc * 32 + l15) * BP + kb];
                    frag8 b1 = *(const frag8*)&xT[(wc * 32 + 16 + l15) * BP + kb];
                    #pragma unroll
                    for (int tr = 0; tr < 4; ++tr) {
                        frag8 a = *(const frag8*)&ybuf[(wr * 64 + tr * 16 + l15) * BP + kb];
                        acc[tr][0] = __builtin_amdgcn_mfma_f32_16x16x32_bf16(a, b0, acc[tr][0], 0, 0, 0);
                        acc[tr][1] = __builtin_amdgcn_mfma_f32_16x16x32_bf16(a, b1, acc[tr][1], 0, 0, 0);
                    }
                }
                __syncthreads();
                #pragma unroll
                for (int tr = 0; tr < 4; ++tr)
                    #pragma unroll
                    for (int c2 = 0; c2 < 2; ++c2) {
                        const int n  = wc * 32 + c2 * 16 + l15;
                        const int m0 = wr * 64 + tr * 16 + quad * 4;
                        f32x4 v = acc[tr][c2];
                        ybuf[(m0 + 0) * BP + n] = bf16c(v[0]);
                        ybuf[(m0 + 1) * BP + n] = bf16c(v[1]);
                        ybuf[(m0 + 2) * BP + n] = bf16c(v[2]);
                        ybuf[(m0 + 3) * BP + n] = bf16c(v[3]);
                    }
            }
            __syncthreads();

            mm_xw2(ybuf, xT, wf2, wr, wc, l15, quad, lane, &s_S);
            ss = s_S;
            skip = (ss == 0.0f) || (wok && ss < EPS);
        }
    }
}

extern "C" void kernel_launch(void* const* d_in, const int* in_sizes, int n_in,
                              void* d_out, int out_size, void* d_ws, size_t ws_size,
                              hipStream_t stream) {
    const float* x = (const float*)d_in[0];   // (32,128,128) fp32
    const float* W = (const float*)d_in[1];   // (128,128) fp32
    float* out = (float*)d_out;               // (32,128,128) fp32

    const size_t shmem = (size_t)NN * AP * sizeof(float)
                       + (size_t)2 * NN * BP * sizeof(short)
                       + (size_t)3 * NN * sizeof(float);   // 138,752 B (full path)
    hipFuncSetAttribute((const void*)gcn_kernel,
                        hipFuncAttributeMaxDynamicSharedMemorySize, (int)shmem);

    gcn_kernel<<<dim3(BATCH), dim3(NT), shmem, stream>>>(x, W, out);
}

// Round 8
// 79.579 us; speedup vs baseline: 1.0045x; 1.0045x over previous
//
#include <hip/hip_runtime.h>
#include <math.h>

// (B, N, D) = (32, 128, 128)
#define BATCH 32
#define NN    128
#define AP    132     // full-path adjf fp32 pitch
#define BP    136     // bf16 pitch (shorts); rows 272B -> 16B aligned
#define NT    512     // 8 waves
#define EPS   6e-3f
#define MROW  32      // fast path window (certified via ||W||_F powers)

typedef short frag8 __attribute__((ext_vector_type(8)));
typedef float f32x4 __attribute__((ext_vector_type(4)));

__device__ __forceinline__ short bf16c(float f) {
    unsigned u = __float_as_uint(f);
    unsigned r = (u + 0x7fffu + ((u >> 16) & 1u)) >> 16;
    return (short)r;
}
__device__ __forceinline__ float bf2f(short s) {
    return __uint_as_float(((unsigned)(unsigned short)s) << 16);
}

// ---------- full-path helper (round-6, validated) ----------
__device__ void mm_xw2(short* __restrict__ abuf, short* __restrict__ xT,
                       const frag8 wf[4][2], int wr, int wc, int l15, int quad,
                       int lane, float* ssp) {
    const f32x4 z = {0.f, 0.f, 0.f, 0.f};
    f32x4 acc[4][2];
    #pragma unroll
    for (int tr = 0; tr < 4; ++tr) { acc[tr][0] = z; acc[tr][1] = z; }
    #pragma unroll
    for (int ks = 0; ks < 4; ++ks) {
        const int kb = ks * 32 + quad * 8;
        #pragma unroll
        for (int tr = 0; tr < 4; ++tr) {
            frag8 a = *(const frag8*)&abuf[(wr * 64 + tr * 16 + l15) * BP + kb];
            acc[tr][0] = __builtin_amdgcn_mfma_f32_16x16x32_bf16(a, wf[ks][0], acc[tr][0], 0, 0, 0);
            acc[tr][1] = __builtin_amdgcn_mfma_f32_16x16x32_bf16(a, wf[ks][1], acc[tr][1], 0, 0, 0);
        }
    }
    __syncthreads();
    float lss = 0.f;
    #pragma unroll
    for (int tr = 0; tr < 4; ++tr)
        #pragma unroll
        for (int c2 = 0; c2 < 2; ++c2) {
            const int n  = wc * 32 + c2 * 16 + l15;
            const int m0 = wr * 64 + tr * 16 + quad * 4;
            f32x4 v = acc[tr][c2];
            float r0 = v[0] > 0.f ? v[0] : 0.f;
            float r1 = v[1] > 0.f ? v[1] : 0.f;
            float r2 = v[2] > 0.f ? v[2] : 0.f;
            float r3 = v[3] > 0.f ? v[3] : 0.f;
            lss = fmaf(r0, r0, lss); lss = fmaf(r1, r1, lss);
            lss = fmaf(r2, r2, lss); lss = fmaf(r3, r3, lss);
            short4 p; p.x = bf16c(r0); p.y = bf16c(r1);
            p.z = bf16c(r2); p.w = bf16c(r3);
            *(short4*)&xT[n * BP + m0] = p;
            abuf[(m0 + 0) * BP + n] = p.x;
            abuf[(m0 + 1) * BP + n] = p.y;
            abuf[(m0 + 2) * BP + n] = p.z;
            abuf[(m0 + 3) * BP + n] = p.w;
        }
    #pragma unroll
    for (int off = 32; off >= 1; off >>= 1) lss += __shfl_down(lss, off);
    if (lane == 0) atomicAdd(ssp, lss);
    __syncthreads();
}

__global__ __launch_bounds__(NT, 1)
void gcn_kernel(const float* __restrict__ xin,
                const float* __restrict__ W,
                float* __restrict__ out) {
    extern __shared__ char smem_raw[];
    __shared__ float s_wn, s_x0max, s_aii, s_sprob;
    __shared__ float sSb[2];

    const int t = threadIdx.x;
    const int b = blockIdx.x;
    const int lane = t & 63, w = t >> 6;
    const int l15 = lane & 15, quad = lane >> 4;

    const float* xin_b = xin + (size_t)b * NN * NN;
    float*       out_b = out + (size_t)b * NN * NN;

    // =============== prelude =================================================
    float* rowsq = (float*)smem_raw;               // [128] prelude-only
    short* wt = (short*)(smem_raw + 512);          // [128][BP] bf16 W^T
    short* xa = wt + NN * BP;                      // [32][BP]  bf16 window x

    if (t == 0) { s_wn = 0.f; s_x0max = 0.f; sSb[0] = 0.f; sSb[1] = 0.f; }
    __syncthreads();

    // zero output + diagonal in one pass
    #pragma unroll
    for (int k = 0; k < 8; ++k) {
        const int v = k * NT + t;                  // float4 idx < 4096
        const int r = v >> 5, c0 = (v & 31) * 4;
        float4 zz = {0.f, 0.f, 0.f, 0.f};
        if (r >= c0 && r < c0 + 4) ((float*)&zz)[r - c0] = 1.0f;
        ((float4*)out_b)[v] = zz;
    }
    // W -> wt (bf16 transposed) + ||W||_F^2
    {
        float lw = 0.f;
        #pragma unroll
        for (int k = 0; k < 8; ++k) {
            const int idx = k * NT + t;
            float4 f = ((const float4*)W)[idx];
            lw = fmaf(f.x, f.x, lw); lw = fmaf(f.y, f.y, lw);
            lw = fmaf(f.z, f.z, lw); lw = fmaf(f.w, f.w, lw);
            const int e0 = idx * 4, d = e0 >> 7, e = e0 & 127;
            wt[(e + 0) * BP + d] = bf16c(f.x);
            wt[(e + 1) * BP + d] = bf16c(f.y);
            wt[(e + 2) * BP + d] = bf16c(f.z);
            wt[(e + 3) * BP + d] = bf16c(f.w);
        }
        #pragma unroll
        for (int off = 32; off >= 1; off >>= 1) lw += __shfl_down(lw, off);
        if (lane == 0) atomicAdd(&s_wn, lw);
    }
    // xin rows 0..31 -> xa (bf16)
    #pragma unroll
    for (int k = 0; k < 2; ++k) {
        const int v = k * NT + t;                  // < 1024
        float4 f = ((const float4*)xin_b)[v];
        const int r = v >> 5, c = (v & 31) * 4;
        short4 p; p.x = bf16c(f.x); p.y = bf16c(f.y); p.z = bf16c(f.z); p.w = bf16c(f.w);
        *(short4*)&xa[r * BP + c] = p;
    }
    // per-row ||xin_r||^2 via half-wave shuffles (32 consecutive threads = 1 row)
    #pragma unroll
    for (int k = 0; k < 8; ++k) {
        const int v = k * NT + t;
        float4 f = ((const float4*)xin_b)[v];
        float s = fmaf(f.x, f.x, fmaf(f.y, f.y, fmaf(f.z, f.z, f.w * f.w)));
        s += __shfl_down(s, 16, 32); s += __shfl_down(s, 8, 32);
        s += __shfl_down(s, 4, 32);  s += __shfl_down(s, 2, 32);
        s += __shfl_down(s, 1, 32);
        if ((t & 31) == 0) rowsq[k * 16 + (t >> 5)] = s;
    }
    __syncthreads();
    if (t < NN) atomicMax((int*)&s_x0max, __float_as_int(rowsq[t]));
    __syncthreads();
    const float wn = s_wn;
    bool fast;
    {
        float u = s_x0max;
        #pragma unroll
        for (int k = 0; k < 32; ++k) u *= wn;      // X0max * wn^32
        fast = (wn <= 1.0f) && (u < EPS);
    }

    // =============== FAST PATH: wave-redundant small phases ==================
    float* adjw_all = (float*)(xa + MROW * BP);    // [8][32*33]
    float* pw_all   = adjw_all + 8 * 32 * 33;      // [8][32]
    float* rsw_all  = pw_all + 8 * 32;             // [8][2][32]
    float* dvw_all  = rsw_all + 8 * 64;            // [8][32]
    float* adjw = adjw_all + w * (32 * 33);
    float* pw   = pw_all + w * 32;
    float* rsw0 = rsw_all + w * 64;
    float* dvw  = dvw_all + w * 32;

    const int rt = w & 1, ct = w >> 1;             // F tile: rows rt*16.., cols ct*32..
    frag8 wfrag[4][2];

    if (fast) {
        if (lane < 32) rsw0[lane] = 1.0f;          // rs buf0 = rowsums of I
        if (lane == 0) adjw[0] = 1.0f;             // adj block starts as [1]
        #pragma unroll
        for (int ks = 0; ks < 4; ++ks)
            #pragma unroll
            for (int c2 = 0; c2 < 2; ++c2) {
                const int e  = ct * 32 + c2 * 16 + l15;
                const int kb = ks * 32 + quad * 8;
                wfrag[ks][c2] = *(const frag8*)&wt[e * BP + kb];
            }
        // x0 = relu(xin[0..31] @ W) -> xa
        {
            frag8 af[4];
            #pragma unroll
            for (int ks = 0; ks < 4; ++ks)
                af[ks] = *(const frag8*)&xa[(rt * 16 + l15) * BP + ks * 32 + quad * 8];
            const f32x4 z = {0.f, 0.f, 0.f, 0.f};
            f32x4 a0 = z, a1 = z;
            #pragma unroll
            for (int ks = 0; ks < 4; ++ks) {
                a0 = __builtin_amdgcn_mfma_f32_16x16x32_bf16(af[ks], wfrag[ks][0], a0, 0, 0, 0);
                a1 = __builtin_amdgcn_mfma_f32_16x16x32_bf16(af[ks], wfrag[ks][1], a1, 0, 0, 0);
            }
            __syncthreads();                       // all xa reads done
            float lss = 0.f;
            #pragma unroll
            for (int c2 = 0; c2 < 2; ++c2) {
                const int e = ct * 32 + c2 * 16 + l15;
                const int m0 = rt * 16 + quad * 4;
                f32x4 v = c2 ? a1 : a0;
                #pragma unroll
                for (int jj = 0; jj < 4; ++jj) {
                    float rr = v[jj] > 0.f ? v[jj] : 0.f;
                    lss = fmaf(rr, rr, lss);
                    xa[(m0 + jj) * BP + e] = bf16c(rr);
                }
            }
            #pragma unroll
            for (int off = 32; off >= 1; off >>= 1) lss += __shfl_down(lss, off);
            if (lane == 0) atomicAdd(&sSb[0], lss);
            __syncthreads();
        }
        // certificate (c): S1 * wn^31 < EPS -> S<EPS strictly before i=32
        {
            float u = sSb[0];
            #pragma unroll
            for (int k = 0; k < 31; ++k) u *= wn;
            if (u >= EPS) fast = false;
        }
    }

    if (fast) {
        bool skip = (sSb[0] < EPS);
        for (int i = 1; i < MROW && !skip; ++i) {
            const int par = i & 1;
            float* rs_rd = rsw0 + ((par ^ 1) * 32);
            float* rs_wr = rsw0 + (par * 32);

            // --- P: prob dots, wave-redundant (4 lanes per dot), no barrier
            float sprob;
            {
                const int jq = lane >> 2, q = lane & 3;
                float sp = 0.f;
                const int npass = ((i - 1) >> 4) + 1;
                for (int p = 0; p < npass; ++p) {
                    const int j = p * 16 + jq;
                    if (j < i) {
                        float s = 0.f;
                        #pragma unroll
                        for (int dd = 0; dd < 4; ++dd) {
                            frag8 aj = *(const frag8*)&xa[j * BP + q * 32 + dd * 8];
                            frag8 ai = *(const frag8*)&xa[i * BP + q * 32 + dd * 8];
                            #pragma unroll
                            for (int u2 = 0; u2 < 8; ++u2)
                                s = fmaf(bf2f(aj[u2]), bf2f(ai[u2]), s);
                        }
                        s += __shfl_down(s, 2, 4);
                        s += __shfl_down(s, 1, 4);
                        if (q == 0) {
                            pw[j] = s;
                            if (w == 0) { out_b[i * NN + j] = s; out_b[j * NN + i] = s; }
                            sp += s;
                        }
                    }
                }
                #pragma unroll
                for (int off = 32; off >= 1; off >>= 1) sp += __shfl_down(sp, off);
                sprob = __shfl(sp, 0);
            }
            // --- Q: dinv, wave-local
            if (lane < 32) {
                const int c = lane;
                float dv = 0.f;
                if (c <= i) dv = 1.0f / sqrtf((c == i) ? (1.f + sprob)
                                                       : (rs_rd[c] + pw[c]));
                dvw[c] = dv;
            }
            // --- D: extend+normalize adj block, new rowsums (parity dbuf)
            {
                const int r = lane >> 1, cs = (lane & 1) * 16;
                const float drr = dvw[r];
                float part = 0.f;
                for (int g = 0; g < 16; ++g) {
                    const int c = cs + g;
                    if (r <= i && c <= i) {
                        float val;
                        if (r == i) val = (c == i) ? 1.f : pw[c];
                        else        val = (c == i) ? pw[r] : adjw[r * 33 + c];
                        float nv = drr * val * dvw[c];
                        adjw[r * 33 + c] = nv;
                        part += nv;
                    }
                }
                part += __shfl_down(part, 1, 2);
                if ((lane & 1) == 0 && r <= i) rs_wr[r] = part;
            }
            // --- E+F fused: y built in registers, straight into MFMA A-frag
            {
                const int r = rt * 16 + l15;
                frag8 af[4];
                if (r <= i) {
                    float yv[32];
                    #pragma unroll
                    for (int u2 = 0; u2 < 32; ++u2) yv[u2] = 0.f;
                    for (int c = 0; c <= i; ++c) {
                        const float av = adjw[r * 33 + c];
                        #pragma unroll
                        for (int ks = 0; ks < 4; ++ks) {
                            frag8 xc = *(const frag8*)&xa[c * BP + ks * 32 + quad * 8];
                            #pragma unroll
                            for (int e2 = 0; e2 < 8; ++e2)
                                yv[ks * 8 + e2] = fmaf(av, bf2f(xc[e2]), yv[ks * 8 + e2]);
                        }
                    }
                    #pragma unroll
                    for (int ks = 0; ks < 4; ++ks)
                        #pragma unroll
                        for (int e2 = 0; e2 < 8; ++e2)
                            af[ks][e2] = bf16c(yv[ks * 8 + e2]);
                } else {
                    #pragma unroll
                    for (int ks = 0; ks < 4; ++ks)
                        af[ks] = *(const frag8*)&xa[r * BP + ks * 32 + quad * 8];
                }
                const f32x4 z = {0.f, 0.f, 0.f, 0.f};
                f32x4 a0 = z, a1 = z;
                #pragma unroll
                for (int ks = 0; ks < 4; ++ks) {
                    a0 = __builtin_amdgcn_mfma_f32_16x16x32_bf16(af[ks], wfrag[ks][0], a0, 0, 0, 0);
                    a1 = __builtin_amdgcn_mfma_f32_16x16x32_bf16(af[ks], wfrag[ks][1], a1, 0, 0, 0);
                }
                __syncthreads();                   // all xa reads (P+E) done
                if (t == NT - 1) sSb[par ^ 1] = 0.f;  // safe: behind mid barrier
                float lss = 0.f;
                #pragma unroll
                for (int c2 = 0; c2 < 2; ++c2) {
                    const int e = ct * 32 + c2 * 16 + l15;
                    const int m0 = rt * 16 + quad * 4;
                    f32x4 v = c2 ? a1 : a0;
                    #pragma unroll
                    for (int jj = 0; jj < 4; ++jj) {
                        float rr = v[jj] > 0.f ? v[jj] : 0.f;
                        lss = fmaf(rr, rr, lss);
                        xa[(m0 + jj) * BP + e] = bf16c(rr);
                    }
                }
                #pragma unroll
                for (int off = 32; off >= 1; off >>= 1) lss += __shfl_down(lss, off);
                if (lane == 0) atomicAdd(&sSb[par], lss);
                __syncthreads();
            }
            skip = (sSb[par] < EPS);
        }
        return;
    }

    // =============== FULL PATH (round-6/7, validated fallback) ===============
    {
        float* adjf = (float*)smem_raw;            // [128][132]
        short* ybuf = (short*)(adjf + NN * AP);    // [128][136]
        short* xT   = ybuf + NN * BP;              // [128][136]
        float* prob = (float*)(xT + NN * BP);      // [128]
        float* dinv = prob + NN;                   // [128]
        float* rs   = dinv + NN;                   // [128]

        const int wr = w >> 2, wc = w & 3;

        if (t == 0) { sSb[0] = 0.0f; s_sprob = 0.0f; }
        __syncthreads();

        for (int e = t; e < NN * AP; e += NT) adjf[e] = 0.0f;
        for (int v = t; v < NN * NN / 4; v += NT) {
            float4 f = ((const float4*)xin_b)[v];
            const int node = v >> 5, c = (v & 31) * 4;
            short4 p; p.x = bf16c(f.x); p.y = bf16c(f.y); p.z = bf16c(f.z); p.w = bf16c(f.w);
            *(short4*)&ybuf[node * BP + c] = p;
        }
        #pragma unroll
        for (int k = 0; k < 8; ++k) {
            const int idx = k * NT + t;
            float4 f = ((const float4*)W)[idx];
            const int e0 = idx * 4, d = e0 >> 7, e = e0 & 127;
            xT[(e + 0) * BP + d] = bf16c(f.x);
            xT[(e + 1) * BP + d] = bf16c(f.y);
            xT[(e + 2) * BP + d] = bf16c(f.z);
            xT[(e + 3) * BP + d] = bf16c(f.w);
        }
        __syncthreads();

        frag8 wf2[4][2];
        #pragma unroll
        for (int ks = 0; ks < 4; ++ks)
            #pragma unroll
            for (int c2 = 0; c2 < 2; ++c2) {
                const int e  = wc * 32 + c2 * 16 + l15;
                const int kb = ks * 32 + quad * 8;
                wf2[ks][c2] = *(const frag8*)&xT[e * BP + kb];
            }
        if (t < NN) {
            adjf[t * AP + t] = 1.0f;
            out_b[t * NN + t] = 1.0f;
            rs[t] = 1.0f;
        }
        const bool wok = (wn <= 1.0f);
        __syncthreads();

        mm_xw2(ybuf, xT, wf2, wr, wc, l15, quad, lane, &sSb[0]);
        float ss = sSb[0];
        bool skip = (ss == 0.0f) || (wok && ss < EPS);

        for (int i = 1; i < NN; ++i) {
            if (skip) {
                const int i0 = i;
                const int nrow = NN - i0;
                for (int v = t; v < nrow * (NN / 4); v += NT) {
                    const int r = i0 + (v >> 5), c = (v & 31) * 4;
                    float4 zz = {0.f, 0.f, 0.f, 0.f};
                    *(float4*)&out_b[r * NN + c] = zz;
                }
                for (int v = t; v < i0 * nrow; v += NT) {
                    const int r = v / nrow, c = i0 + v % nrow;
                    out_b[r * NN + c] = 0.f;
                }
                __syncthreads();
                if (t >= i0 && t < NN) out_b[t * NN + t] = 1.0f;
                break;
            }

            {
                if (t == 0) s_aii = adjf[i * AP + i];
                const f32x4 z = {0.f, 0.f, 0.f, 0.f};
                f32x4 pa = z, pb = z;
                #pragma unroll
                for (int ks = 0; ks < 4; ++ks) {
                    const int kb = ks * 32 + quad * 8;
                    frag8 a  = *(const frag8*)&ybuf[(w * 16 + l15) * BP + kb];
                    frag8 bb = *(const frag8*)&ybuf[i * BP + kb];
                    if (ks & 1) pb = __builtin_amdgcn_mfma_f32_16x16x32_bf16(a, bb, pb, 0, 0, 0);
                    else        pa = __builtin_amdgcn_mfma_f32_16x16x32_bf16(a, bb, pa, 0, 0, 0);
                }
                f32x4 pc = pa + pb;
                float sp = 0.f;
                if (l15 == 0) {
                    #pragma unroll
                    for (int r = 0; r < 4; ++r) {
                        const int j = w * 16 + quad * 4 + r;
                        const float p = pc[r];
                        const bool m = (j < i);
                        prob[j] = m ? p : 0.f;
                        if (m) {
                            adjf[i * AP + j] = p;  adjf[j * AP + i] = p;
                            out_b[i * NN + j] = p; out_b[j * NN + i] = p;
                            sp += p;
                        }
                    }
                }
                sp += __shfl_down(sp, 32);
                sp += __shfl_down(sp, 16);
                if (lane == 0) atomicAdd(&s_sprob, sp);
            }
            __syncthreads();

            if (t < NN) {
                const float d = (t == i) ? (s_aii + s_sprob) : (rs[t] + prob[t]);
                dinv[t] = 1.0f / sqrtf(d);
            }
            if (t == NN) sSb[0] = 0.f;
            __syncthreads();

            {
                const int r = t >> 2, q = t & 3;
                const float dr = dinv[r];
                float lrs = 0.f;
                #pragma unroll
                for (int g = 0; g < 8; ++g) {
                    const int c = q * 32 + g * 4;
                    float4 v4 = *(const float4*)&adjf[r * AP + c];
                    float4 d4 = *(const float4*)&dinv[c];
                    v4.x *= dr * d4.x; v4.y *= dr * d4.y;
                    v4.z *= dr * d4.z; v4.w *= dr * d4.w;
                    *(float4*)&adjf[r * AP + c] = v4;
                    lrs += (v4.x + v4.y) + (v4.z + v4.w);
                    short4 p; p.x = bf16c(v4.x); p.y = bf16c(v4.y);
                    p.z = bf16c(v4.z); p.w = bf16c(v4.w);
                    *(short4*)&ybuf[r * BP + c] = p;
                }
                lrs += __shfl_down(lrs, 2, 4);
                lrs += __shfl_down(lrs, 1, 4);
                if (q == 0) rs[r] = lrs;
                if (t == NT - 1) s_sprob = 0.f;
            }
            __syncthreads();

            {
                const f32x4 z = {0.f, 0.f, 0.f, 0.f};
                f32x4 acc[4][2];
                #pragma unroll
                for (int tr = 0; tr < 4; ++tr) { acc[tr][0] = z; acc[tr][1] = z; }
                #pragma unroll
                for (int ks = 0; ks < 4; ++ks) {
                    const int kb = ks * 32 + quad * 8;
                    frag8 b0 = *(const frag8*)&xT[(wc * 32 + l15) * BP + kb];
                    frag8 b1 = *(const frag8*)&xT[(wc * 32 + 16 + l15) * BP + kb];
                    #pragma unroll
                    for (int tr = 0; tr < 4; ++tr) {
                        frag8 a = *(const frag8*)&ybuf[(wr * 64 + tr * 16 + l15) * BP + kb];
                        acc[tr][0] = __builtin_amdgcn_mfma_f32_16x16x32_bf16(a, b0, acc[tr][0], 0, 0, 0);
                        acc[tr][1] = __builtin_amdgcn_mfma_f32_16x16x32_bf16(a, b1, acc[tr][1], 0, 0, 0);
                    }
                }
                __syncthreads();
                #pragma unroll
                for (int tr = 0; tr < 4; ++tr)
                    #pragma unroll
                    for (int c2 = 0; c2 < 2; ++c2) {
                        const int n  = wc * 32 + c2 * 16 + l15;
                        const int m0 = wr * 64 + tr * 16 + quad * 4;
                        f32x4 v = acc[tr][c2];
                        ybuf[(m0 + 0) * BP + n] = bf16c(v[0]);
                        ybuf[(m0 + 1) * BP + n] = bf16c(v[1]);
                        ybuf[(m0 + 2) * BP + n] = bf16c(v[2]);
                        ybuf[(m0 + 3) * BP + n] = bf16c(v[3]);
                    }
            }
            __syncthreads();

            mm_xw2(ybuf, xT, wf2, wr, wc, l15, quad, lane, &sSb[0]);
            ss = sSb[0];
            skip = (ss == 0.0f) || (wok && ss < EPS);
        }
    }
}

extern "C" void kernel_launch(void* const* d_in, const int* in_sizes, int n_in,
                              void* d_out, int out_size, void* d_ws, size_t ws_size,
                              hipStream_t stream) {
    const float* x = (const float*)d_in[0];   // (32,128,128) fp32
    const float* W = (const float*)d_in[1];   // (128,128) fp32
    float* out = (float*)d_out;               // (32,128,128) fp32

    const size_t shmem = (size_t)NN * AP * sizeof(float)
                       + (size_t)2 * NN * BP * sizeof(short)
                       + (size_t)3 * NN * sizeof(float);   // 138,752 B (full path max)
    hipFuncSetAttribute((const void*)gcn_kernel,
                        hipFuncAttributeMaxDynamicSharedMemorySize, (int)shmem);

    gcn_kernel<<<dim3(BATCH), dim3(NT), shmem, stream>>>(x, W, out);
}